// Round 10
// baseline (2853.855 us; speedup 1.0000x reference)
//
#include <hip/hip_runtime.h>

typedef unsigned short u16;
typedef unsigned int u32;
typedef __attribute__((ext_vector_type(8))) unsigned short u16x8;
typedef __attribute__((ext_vector_type(4))) float f32x4;

#define NTOK 131072  // 16384 * 8 tokens

__device__ __forceinline__ float b2f(u16 v) {
  return __uint_as_float(((u32)v) << 16);
}
__device__ __forceinline__ u16 f2b(float f) {
  u32 u = __float_as_uint(f);
  u32 r = u + 0x7fffu + ((u >> 16) & 1u);
  return (u16)(r >> 16);
}

__device__ __forceinline__ void gload16(const void* g, void* l) {
  __builtin_amdgcn_global_load_lds((const __attribute__((address_space(1))) void*)g,
                                   (__attribute__((address_space(3))) void*)l, 16, 0, 0);
}

__device__ __forceinline__ void mfma16(f32x4& c, u16x8 a, u16x8 b) {
  asm("v_mfma_f32_16x16x32_bf16 %0, %1, %2, %0" : "+v"(c) : "v"(a), "v"(b));
}

#define BAR() __builtin_amdgcn_s_barrier()
#define VM(n) asm volatile("s_waitcnt vmcnt(" #n ")" ::: "memory")
#define PRIO1() __builtin_amdgcn_s_setprio(1)
#define PRIO0() __builtin_amdgcn_s_setprio(0)

// ---------------- sinusoid table [8][512] ----------------
__global__ __launch_bounds__(256) void table_kernel(float* __restrict__ tab) {
  const int i = blockIdx.x * 256 + threadIdx.x;
  if (i >= 4096) return;
  const int p = i >> 9, j = i & 511;
  const float ex = 2.f * (float)(j >> 1) / 512.f;
  const float ang = (float)p * powf(10000.f, -ex);
  tab[i] = (j & 1) ? cosf(ang) : sinf(ang);
}

// ---------------- pack bq|bk|bv -> [L][1536] ----------------
__global__ __launch_bounds__(256) void biaspack_kernel(const float* __restrict__ bq,
                                                       const float* __restrict__ bk,
                                                       const float* __restrict__ bv,
                                                       float* __restrict__ dst) {
  const int i = blockIdx.x * 256 + threadIdx.x;
  if (i >= 3072) return;
  const int l = i / 1536, j = i % 1536;
  float v;
  if (j < 512) v = bq[l * 512 + j];
  else if (j < 1024) v = bk[l * 512 + j - 512];
  else v = bv[l * 512 + j - 1024];
  dst[i] = v;
}

// ---------------- weight transpose+convert fp32[K][N] -> bf16[N][K] ----------------
struct TJob { const float* src; u16* dst; int Ki, Ni, blk0; };
struct TJobs { TJob j[12]; };

__global__ __launch_bounds__(256) void wconv_kernel(TJobs jobs) {
  __shared__ float tile[64][65];
  const int bid = blockIdx.x;
  int ji = 0;
#pragma unroll
  for (int t = 1; t < 12; ++t)
    if (bid >= jobs.j[t].blk0) ji = t;
  const TJob J = jobs.j[ji];
  const int rel = bid - J.blk0;
  const int ntn = J.Ni >> 6;
  const int tk = rel / ntn, tn = rel % ntn;
  const int tid = threadIdx.x;
  const int cn = tid & 63, rk = tid >> 6;
#pragma unroll
  for (int r = 0; r < 16; ++r) {
    const int kk = rk + r * 4;
    tile[kk][cn] = J.src[(size_t)(tk * 64 + kk) * J.Ni + tn * 64 + cn];
  }
  __syncthreads();
  const int ck = tid & 63, rn = tid >> 6;
#pragma unroll
  for (int r = 0; r < 16; ++r) {
    const int nn = rn + r * 4;
    J.dst[(size_t)(tn * 64 + nn) * J.Ki + tk * 64 + ck] = f2b(tile[ck][nn]);
  }
}

// ---------------- posenc: h_bf16 = x_fp32 + tab[s][:] ----------------
__global__ __launch_bounds__(256) void posenc_kernel(const float* __restrict__ x,
                                                     const float* __restrict__ tab,
                                                     u16* __restrict__ h) {
  const int i = blockIdx.x * 256 + threadIdx.x;
  const size_t e0 = (size_t)i * 8;
  const int d = (int)(e0 & 511);
  const int srow = (int)((e0 >> 9) & 7);
  const float4 a0 = *(const float4*)(x + e0);
  const float4 a1 = *(const float4*)(x + e0 + 4);
  const float* tp = tab + srow * 512 + d;
  float v[8] = {a0.x, a0.y, a0.z, a0.w, a1.x, a1.y, a1.z, a1.w};
  u16x8 o;
#pragma unroll
  for (int e = 0; e < 8; ++e) o[e] = f2b(v[e] + tp[e]);
  *(u16x8*)(h + e0) = o;
}

// ================== GEMM 256x256 (round-6 config): 4-window K-loop ==================
#define RDA(c, mh)                                                                  \
  A0 = *(const u16x8*)&As[c][wrbase + ((((mh) << 6) + 0 + lr) << 6) + swk0];        \
  A1 = *(const u16x8*)&As[c][wrbase + ((((mh) << 6) + 0 + lr) << 6) + swk1];        \
  A2 = *(const u16x8*)&As[c][wrbase + ((((mh) << 6) + 16 + lr) << 6) + swk0];       \
  A3 = *(const u16x8*)&As[c][wrbase + ((((mh) << 6) + 16 + lr) << 6) + swk1];       \
  A4 = *(const u16x8*)&As[c][wrbase + ((((mh) << 6) + 32 + lr) << 6) + swk0];       \
  A5 = *(const u16x8*)&As[c][wrbase + ((((mh) << 6) + 32 + lr) << 6) + swk1];       \
  A6 = *(const u16x8*)&As[c][wrbase + ((((mh) << 6) + 48 + lr) << 6) + swk0];       \
  A7 = *(const u16x8*)&As[c][wrbase + ((((mh) << 6) + 48 + lr) << 6) + swk1]

#define RDB(c, nh, V00, V01, V10, V11)                                                   \
  V00 = *(const u16x8*)&Bs[c][wcbase + ((brow0 + (((nh) << 1) + 0) * 16 + lr) << 6) + swk0]; \
  V01 = *(const u16x8*)&Bs[c][wcbase + ((brow0 + (((nh) << 1) + 0) * 16 + lr) << 6) + swk1]; \
  V10 = *(const u16x8*)&Bs[c][wcbase + ((brow0 + (((nh) << 1) + 1) * 16 + lr) << 6) + swk0]; \
  V11 = *(const u16x8*)&Bs[c][wcbase + ((brow0 + (((nh) << 1) + 1) * 16 + lr) << 6) + swk1]

#define QM(mh, nh, V00, V01, V10, V11)                \
  mfma16(acc[((mh) << 2) + 0][((nh) << 1) + 0], A0, V00); \
  mfma16(acc[((mh) << 2) + 0][((nh) << 1) + 1], A0, V10); \
  mfma16(acc[((mh) << 2) + 1][((nh) << 1) + 0], A2, V00); \
  mfma16(acc[((mh) << 2) + 1][((nh) << 1) + 1], A2, V10); \
  mfma16(acc[((mh) << 2) + 2][((nh) << 1) + 0], A4, V00); \
  mfma16(acc[((mh) << 2) + 2][((nh) << 1) + 1], A4, V10); \
  mfma16(acc[((mh) << 2) + 3][((nh) << 1) + 0], A6, V00); \
  mfma16(acc[((mh) << 2) + 3][((nh) << 1) + 1], A6, V10); \
  mfma16(acc[((mh) << 2) + 0][((nh) << 1) + 0], A1, V01); \
  mfma16(acc[((mh) << 2) + 0][((nh) << 1) + 1], A1, V11); \
  mfma16(acc[((mh) << 2) + 1][((nh) << 1) + 0], A3, V01); \
  mfma16(acc[((mh) << 2) + 1][((nh) << 1) + 1], A3, V11); \
  mfma16(acc[((mh) << 2) + 2][((nh) << 1) + 0], A5, V01); \
  mfma16(acc[((mh) << 2) + 2][((nh) << 1) + 1], A5, V11); \
  mfma16(acc[((mh) << 2) + 3][((nh) << 1) + 0], A7, V01); \
  mfma16(acc[((mh) << 2) + 3][((nh) << 1) + 1], A7, V11)

template <int RELU>
__global__ __launch_bounds__(512, 1) void gemm256(const u16* __restrict__ A,
                                                  const u16* __restrict__ Bt,
                                                  const float* __restrict__ bias,
                                                  u16* __restrict__ C, int M, int N, int K) {
  __shared__ __align__(16) u16 As[2][16384];
  __shared__ __align__(16) u16 Bs[2][16384];
  const int nbn = N >> 8;
  const int cpx = gridDim.x >> 3;
  const int bid = blockIdx.x;
  const int wgid = (bid & 7) * cpx + (bid >> 3);
  const int bm = wgid / nbn, bn = wgid - bm * nbn;
  const int tid = threadIdx.x;
  const int wid = tid >> 6, lane = tid & 63;
  const int wr = wid >> 2, wc = wid & 3;
  const int lr = lane & 15, kg0 = lane >> 4;
  const int swk0 = ((kg0 ^ (lr & 7)) << 3);
  const int swk1 = (((kg0 + 4) ^ (lr & 7)) << 3);
  const int wrbase = wr << 13;
  const int wcbase = (wc >> 1) << 13;
  const int brow0 = (wc & 1) << 6;
  const int rowinc = tid >> 3;
  const int gcol = (((tid & 7) ^ (rowinc & 7)) << 3);
  const u16* Ag = A + (size_t)((bm << 8) + rowinc) * K + gcol;
  const u16* Bg = Bt + (size_t)((bn << 8) + rowinc) * K + gcol;
  const int ldsw = wid << 9;

  f32x4 acc[8][4];
  const f32x4 zero = {0.f, 0.f, 0.f, 0.f};
#pragma unroll
  for (int m = 0; m < 8; ++m)
#pragma unroll
    for (int n = 0; n < 4; ++n) acc[m][n] = zero;

  u16x8 A0, A1, A2, A3, A4, A5, A6, A7;
  u16x8 B00, B01, B10, B11;
  u16x8 C00, C01, C10, C11;

  auto stgA = [&](int c, int h, int koff) {
    gload16(Ag + (size_t)(h << 7) * K + koff, &As[c][(h << 13) + ldsw]);
    gload16(Ag + (size_t)((h << 7) + 64) * K + koff, &As[c][(h << 13) + 4096 + ldsw]);
  };
  auto stgB = [&](int c, int h, int koff) {
    gload16(Bg + (size_t)(h << 7) * K + koff, &Bs[c][(h << 13) + ldsw]);
    gload16(Bg + (size_t)((h << 7) + 64) * K + koff, &Bs[c][(h << 13) + 4096 + ldsw]);
  };

  stgA(0, 0, 0); stgA(0, 1, 0); stgB(0, 0, 0); stgB(0, 1, 0);
  stgB(1, 0, 64); stgB(1, 1, 64);
  VM(4);
  BAR();

  const int niter = K >> 7;
  int k1 = 64, k2 = 128, k3 = 192;
#pragma unroll 1
  for (int i = 0; i < niter - 1; ++i) {
    RDA(0, 0); RDB(0, 0, B00, B01, B10, B11); stgA(1, 0, k1);
    PRIO1(); QM(0, 0, B00, B01, B10, B11); PRIO0();
    RDB(0, 1, C00, C01, C10, C11); stgA(1, 1, k1);
    PRIO1(); QM(0, 1, C00, C01, C10, C11); PRIO0(); BAR();
    RDA(0, 1); stgB(0, 0, k2);
    PRIO1(); QM(1, 1, C00, C01, C10, C11); PRIO0();
    stgB(0, 1, k2);
    PRIO1(); QM(1, 0, B00, B01, B10, B11); PRIO0(); VM(4); BAR();
    RDA(1, 0); RDB(1, 0, B00, B01, B10, B11); stgA(0, 0, k2);
    PRIO1(); QM(0, 0, B00, B01, B10, B11); PRIO0();
    RDB(1, 1, C00, C01, C10, C11); stgA(0, 1, k2);
    PRIO1(); QM(0, 1, C00, C01, C10, C11); PRIO0(); BAR();
    RDA(1, 1); stgB(1, 0, k3);
    PRIO1(); QM(1, 1, C00, C01, C10, C11); PRIO0();
    stgB(1, 1, k3);
    PRIO1(); QM(1, 0, B00, B01, B10, B11); PRIO0(); VM(4); BAR();
    k1 += 128; k2 += 128; k3 += 128;
  }
  RDA(0, 0); RDB(0, 0, B00, B01, B10, B11); stgA(1, 0, k1);
  PRIO1(); QM(0, 0, B00, B01, B10, B11); PRIO0();
  RDB(0, 1, C00, C01, C10, C11); stgA(1, 1, k1);
  PRIO1(); QM(0, 1, C00, C01, C10, C11); PRIO0(); BAR();
  RDA(0, 1);
  PRIO1(); QM(1, 1, C00, C01, C10, C11); PRIO0();
  PRIO1(); QM(1, 0, B00, B01, B10, B11); PRIO0(); VM(0); BAR();
  RDA(1, 0); RDB(1, 0, B00, B01, B10, B11);
  PRIO1(); QM(0, 0, B00, B01, B10, B11); PRIO0();
  RDB(1, 1, C00, C01, C10, C11);
  PRIO1(); QM(0, 1, C00, C01, C10, C11); PRIO0(); BAR();
  RDA(1, 1);
  PRIO1(); QM(1, 1, C00, C01, C10, C11); PRIO0();
  PRIO1(); QM(1, 0, B00, B01, B10, B11); PRIO0();

  const int r0 = kg0 << 2;
  const int cc = lr;
#pragma unroll
  for (int m8 = 0; m8 < 8; ++m8) {
    const size_t grow = (size_t)((bm << 8) + (wr << 7) + (m8 << 4) + r0);
#pragma unroll
    for (int n4 = 0; n4 < 4; ++n4) {
      const int gc = (bn << 8) + (wc << 6) + (n4 << 4) + cc;
      const float bv = bias[gc];
#pragma unroll
      for (int rr = 0; rr < 4; ++rr) {
        float v = acc[m8][n4][rr] + bv;
        if (RELU) v = fmaxf(v, 0.f);
        // non-temporal: C lines can't survive in L2 until their consumer anyway;
        // keep L2 for the A/B panels of concurrently-running blocks.
        __builtin_nontemporal_store(f2b(v), &C[(grow + rr) * (size_t)N + gc]);
      }
    }
  }
}

// ---------------- attention: per-wave (b,h); qkv [NTOK][1536] -> ctx [NTOK][512] ----------------
__global__ __launch_bounds__(256) void attn_kernel(const u16* __restrict__ QKV,
                                                   u16* __restrict__ ctx) {
  __shared__ __align__(16) u16 sm[4][3][8][72];
  __shared__ float at[4][8][8];
  const int tid = threadIdx.x;
  const int wid = tid >> 6, lane = tid & 63;
  const int bh = blockIdx.x * 4 + wid;
  const int b = bh >> 3, h = bh & 7;
  const int s = lane >> 3, g = lane & 7;
  const u16* base = QKV + (size_t)(b * 8 + s) * 1536 + h * 64 + g * 8;
#pragma unroll
  for (int t = 0; t < 3; ++t)
    *(u16x8*)&sm[wid][t][s][g * 8] = *(const u16x8*)(base + t * 512);
  __syncthreads();
  float sc = 0.f;
#pragma unroll
  for (int c = 0; c < 8; ++c) {
    const int cg = ((c + g) & 7) * 8;
    u16x8 qv = *(const u16x8*)&sm[wid][0][s][cg];
    u16x8 kv = *(const u16x8*)&sm[wid][1][g][cg];
#pragma unroll
    for (int e = 0; e < 8; ++e) sc += b2f(qv[e]) * b2f(kv[e]);
  }
  sc *= 0.125f;
  float mx = fmaxf(sc, __shfl_xor(sc, 1));
  mx = fmaxf(mx, __shfl_xor(mx, 2));
  mx = fmaxf(mx, __shfl_xor(mx, 4));
  const float ex = __expf(sc - mx);
  float sum = ex;
  sum += __shfl_xor(sum, 1);
  sum += __shfl_xor(sum, 2);
  sum += __shfl_xor(sum, 4);
  at[wid][s][g] = ex / sum;
  __syncthreads();
  float o[8] = {0.f, 0.f, 0.f, 0.f, 0.f, 0.f, 0.f, 0.f};
#pragma unroll
  for (int j = 0; j < 8; ++j) {
    const float a = at[wid][s][j];
    u16x8 vv = *(const u16x8*)&sm[wid][2][j][g * 8];
#pragma unroll
    for (int e = 0; e < 8; ++e) o[e] += a * b2f(vv[e]);
  }
  u16x8 ov;
#pragma unroll
  for (int e = 0; e < 8; ++e) ov[e] = f2b(o[e]);
  *(u16x8*)(ctx + (size_t)(b * 8 + s) * 512 + h * 64 + g * 8) = ov;
}

// ---------------- LayerNorm(tmp + h) -> h (in place); FINAL also gathers fp32 out ----------------
template <int FINAL>
__global__ __launch_bounds__(256) void ln_kernel(const u16* __restrict__ t,
                                                 u16* __restrict__ h,
                                                 const float* __restrict__ gam,
                                                 const float* __restrict__ bet,
                                                 float* __restrict__ out) {
  const int tid = threadIdx.x;
  const int wid = tid >> 6, lane = tid & 63;
  const int row = blockIdx.x * 4 + wid;
  const size_t base = (size_t)row * 512 + lane * 8;
  u16x8 tv = *(const u16x8*)(t + base);
  u16x8 hv = *(const u16x8*)(h + base);
  float x[8];
  float s1 = 0.f, s2 = 0.f;
#pragma unroll
  for (int e = 0; e < 8; ++e) {
    x[e] = b2f(tv[e]) + b2f(hv[e]);
    s1 += x[e];
    s2 += x[e] * x[e];
  }
#pragma unroll
  for (int m = 1; m < 64; m <<= 1) {
    s1 += __shfl_xor(s1, m);
    s2 += __shfl_xor(s2, m);
  }
  const float mu = s1 * (1.f / 512.f);
  const float var = s2 * (1.f / 512.f) - mu * mu;
  const float rs = rsqrtf(var + 1e-6f);
  const float4 g0 = *(const float4*)(gam + lane * 8);
  const float4 g1 = *(const float4*)(gam + lane * 8 + 4);
  const float4 b0 = *(const float4*)(bet + lane * 8);
  const float4 b1 = *(const float4*)(bet + lane * 8 + 4);
  const float gv[8] = {g0.x, g0.y, g0.z, g0.w, g1.x, g1.y, g1.z, g1.w};
  const float bv[8] = {b0.x, b0.y, b0.z, b0.w, b1.x, b1.y, b1.z, b1.w};
  float y[8];
  u16x8 yv;
#pragma unroll
  for (int e = 0; e < 8; ++e) {
    y[e] = (x[e] - mu) * rs * gv[e] + bv[e];
    yv[e] = f2b(y[e]);
  }
  *(u16x8*)(h + base) = yv;
  if (FINAL) {
    const int bb = row >> 3, ss = row & 7;
    if (ss == (bb & 7)) {
      float4* op = (float4*)(out + (size_t)bb * 512 + lane * 8);
      op[0] = make_float4(y[0], y[1], y[2], y[3]);
      op[1] = make_float4(y[4], y[5], y[6], y[7]);
    }
  }
}

static void launch_gemm(const u16* A, const u16* Bt, const float* bias, u16* C, int M, int N,
                        int K, int relu, hipStream_t st) {
  dim3 grid((M >> 8) * (N >> 8));
  if (relu)
    gemm256<1><<<grid, 512, 0, st>>>(A, Bt, bias, C, M, N, K);
  else
    gemm256<0><<<grid, 512, 0, st>>>(A, Bt, bias, C, M, N, K);
}

extern "C" void kernel_launch(void* const* d_in, const int* in_sizes, int n_in, void* d_out,
                              int out_size, void* d_ws, size_t ws_size, hipStream_t stream) {
  const float* x = (const float*)d_in[0];
  const float* Wq = (const float*)d_in[1];
  const float* bq = (const float*)d_in[2];
  const float* Wk = (const float*)d_in[3];
  const float* bk = (const float*)d_in[4];
  const float* Wv = (const float*)d_in[5];
  const float* bv = (const float*)d_in[6];
  const float* Wo = (const float*)d_in[7];
  const float* bo = (const float*)d_in[8];
  const float* ln1g = (const float*)d_in[9];
  const float* ln1b = (const float*)d_in[10];
  const float* W1 = (const float*)d_in[11];
  const float* b1 = (const float*)d_in[12];
  const float* W2 = (const float*)d_in[13];
  const float* b2 = (const float*)d_in[14];
  const float* ln2g = (const float*)d_in[15];
  const float* ln2b = (const float*)d_in[16];
  float* out = (float*)d_out;

  char* ws = (char*)d_ws;
  const size_t o_tab = 0;
  const size_t o_bqkv = 16384;
  const size_t o_w = 28672;
  const size_t o_h = o_w + 12582912;
  const size_t o_buf = o_h + (size_t)NTOK * 512 * 2;
  const size_t o_tmp = o_buf + (size_t)NTOK * 2048 * 2;
  const size_t need = o_tmp + (size_t)NTOK * 512 * 2;
  if (ws_size < need) return;

  float* tab = (float*)(ws + o_tab);
  float* bqkv = (float*)(ws + o_bqkv);
  u16* wbf = (u16*)(ws + o_w);
  u16* h = (u16*)(ws + o_h);
  u16* buf = (u16*)(ws + o_buf);
  u16* ctx = buf + (size_t)NTOK * 1536;
  u16* tmp = (u16*)(ws + o_tmp);

  table_kernel<<<16, 256, 0, stream>>>(tab);
  biaspack_kernel<<<12, 256, 0, stream>>>(bq, bk, bv, bqkv);

  TJobs jobs;
  int blk = 0, nj = 0;
  auto add = [&](const float* s, u16* dmat, int Ki, int Ni) {
    jobs.j[nj].src = s;
    jobs.j[nj].dst = dmat;
    jobs.j[nj].Ki = Ki;
    jobs.j[nj].Ni = Ni;
    jobs.j[nj].blk0 = blk;
    ++nj;
    blk += (Ki / 64) * (Ni / 64);
  };
  for (int l = 0; l < 2; ++l) {
    u16* wl = wbf + (size_t)l * 3145728;
    add(Wq + (size_t)l * 262144, wl, 512, 512);
    add(Wk + (size_t)l * 262144, wl + 262144, 512, 512);
    add(Wv + (size_t)l * 262144, wl + 524288, 512, 512);
    add(Wo + (size_t)l * 262144, wl + 786432, 512, 512);
    add(W1 + (size_t)l * 1048576, wl + 1048576, 512, 2048);
    add(W2 + (size_t)l * 1048576, wl + 2097152, 2048, 512);
  }
  wconv_kernel<<<blk, 256, 0, stream>>>(jobs);
  posenc_kernel<<<32768, 256, 0, stream>>>(x, tab, h);

  for (int l = 0; l < 2; ++l) {
    u16* wl = wbf + (size_t)l * 3145728;
    launch_gemm(h, wl, bqkv + l * 1536, buf, NTOK, 1536, 512, 0, stream);
    attn_kernel<<<32768, 256, 0, stream>>>(buf, ctx);
    launch_gemm(ctx, wl + 786432, bo + l * 512, tmp, NTOK, 512, 512, 0, stream);
    ln_kernel<0><<<32768, 256, 0, stream>>>(tmp, h, ln1g + l * 512, ln1b + l * 512, nullptr);
    launch_gemm(h, wl + 1048576, b1 + l * 2048, buf, NTOK, 2048, 512, 1, stream);
    launch_gemm(buf, wl + 2097152, b2 + l * 512, tmp, NTOK, 512, 2048, 0, stream);
    if (l == 0)
      ln_kernel<0><<<32768, 256, 0, stream>>>(tmp, h, ln2g, ln2b, nullptr);
    else
      ln_kernel<1><<<32768, 256, 0, stream>>>(tmp, h, ln2g + 512, ln2b + 512, out);
  }
}

// Round 11
// 1706.703 us; speedup vs baseline: 1.6721x; 1.6721x over previous
//
#include <hip/hip_runtime.h>

typedef unsigned short u16;
typedef unsigned int u32;
typedef __attribute__((ext_vector_type(8))) unsigned short u16x8;
typedef __attribute__((ext_vector_type(4))) float f32x4;

#define NTOK 131072  // 16384 * 8 tokens
#define NSEL 16384   // selected tokens (one per batch)

__device__ __forceinline__ float b2f(u16 v) {
  return __uint_as_float(((u32)v) << 16);
}
__device__ __forceinline__ u16 f2b(float f) {
  u32 u = __float_as_uint(f);
  u32 r = u + 0x7fffu + ((u >> 16) & 1u);
  return (u16)(r >> 16);
}

__device__ __forceinline__ void gload16(const void* g, void* l) {
  __builtin_amdgcn_global_load_lds((const __attribute__((address_space(1))) void*)g,
                                   (__attribute__((address_space(3))) void*)l, 16, 0, 0);
}

__device__ __forceinline__ void mfma16(f32x4& c, u16x8 a, u16x8 b) {
  asm("v_mfma_f32_16x16x32_bf16 %0, %1, %2, %0" : "+v"(c) : "v"(a), "v"(b));
}

#define BAR() __builtin_amdgcn_s_barrier()
#define VM(n) asm volatile("s_waitcnt vmcnt(" #n ")" ::: "memory")
#define PRIO1() __builtin_amdgcn_s_setprio(1)
#define PRIO0() __builtin_amdgcn_s_setprio(0)

// ---------------- sinusoid table [8][512] ----------------
__global__ __launch_bounds__(256) void table_kernel(float* __restrict__ tab) {
  const int i = blockIdx.x * 256 + threadIdx.x;
  if (i >= 4096) return;
  const int p = i >> 9, j = i & 511;
  const float ex = 2.f * (float)(j >> 1) / 512.f;
  const float ang = (float)p * powf(10000.f, -ex);
  tab[i] = (j & 1) ? cosf(ang) : sinf(ang);
}

// ---------------- pack bq|bk|bv -> [L][1536] ----------------
__global__ __launch_bounds__(256) void biaspack_kernel(const float* __restrict__ bq,
                                                       const float* __restrict__ bk,
                                                       const float* __restrict__ bv,
                                                       float* __restrict__ dst) {
  const int i = blockIdx.x * 256 + threadIdx.x;
  if (i >= 3072) return;
  const int l = i / 1536, j = i % 1536;
  float v;
  if (j < 512) v = bq[l * 512 + j];
  else if (j < 1024) v = bk[l * 512 + j - 512];
  else v = bv[l * 512 + j - 1024];
  dst[i] = v;
}

// ---------------- weight transpose+convert fp32[K][N] -> bf16[N][K] ----------------
struct TJob { const float* src; u16* dst; int Ki, Ni, blk0; };
struct TJobs { TJob j[12]; };

__global__ __launch_bounds__(256) void wconv_kernel(TJobs jobs) {
  __shared__ float tile[64][65];
  const int bid = blockIdx.x;
  int ji = 0;
#pragma unroll
  for (int t = 1; t < 12; ++t)
    if (bid >= jobs.j[t].blk0) ji = t;
  const TJob J = jobs.j[ji];
  const int rel = bid - J.blk0;
  const int ntn = J.Ni >> 6;
  const int tk = rel / ntn, tn = rel % ntn;
  const int tid = threadIdx.x;
  const int cn = tid & 63, rk = tid >> 6;
#pragma unroll
  for (int r = 0; r < 16; ++r) {
    const int kk = rk + r * 4;
    tile[kk][cn] = J.src[(size_t)(tk * 64 + kk) * J.Ni + tn * 64 + cn];
  }
  __syncthreads();
  const int ck = tid & 63, rn = tid >> 6;
#pragma unroll
  for (int r = 0; r < 16; ++r) {
    const int nn = rn + r * 4;
    J.dst[(size_t)(tn * 64 + nn) * J.Ki + tk * 64 + ck] = f2b(tile[ck][nn]);
  }
}

// ---------------- posenc: h_bf16 = x_fp32 + tab[s][:] ----------------
__global__ __launch_bounds__(256) void posenc_kernel(const float* __restrict__ x,
                                                     const float* __restrict__ tab,
                                                     u16* __restrict__ h) {
  const int i = blockIdx.x * 256 + threadIdx.x;
  const size_t e0 = (size_t)i * 8;
  const int d = (int)(e0 & 511);
  const int srow = (int)((e0 >> 9) & 7);
  const float4 a0 = *(const float4*)(x + e0);
  const float4 a1 = *(const float4*)(x + e0 + 4);
  const float* tp = tab + srow * 512 + d;
  float v[8] = {a0.x, a0.y, a0.z, a0.w, a1.x, a1.y, a1.z, a1.w};
  u16x8 o;
#pragma unroll
  for (int e = 0; e < 8; ++e) o[e] = f2b(v[e] + tp[e]);
  *(u16x8*)(h + e0) = o;
}

// ================== GEMM 256x256 (round-6 config): 4-window K-loop ==================
#define RDA(c, mh)                                                                  \
  A0 = *(const u16x8*)&As[c][wrbase + ((((mh) << 6) + 0 + lr) << 6) + swk0];        \
  A1 = *(const u16x8*)&As[c][wrbase + ((((mh) << 6) + 0 + lr) << 6) + swk1];        \
  A2 = *(const u16x8*)&As[c][wrbase + ((((mh) << 6) + 16 + lr) << 6) + swk0];       \
  A3 = *(const u16x8*)&As[c][wrbase + ((((mh) << 6) + 16 + lr) << 6) + swk1];       \
  A4 = *(const u16x8*)&As[c][wrbase + ((((mh) << 6) + 32 + lr) << 6) + swk0];       \
  A5 = *(const u16x8*)&As[c][wrbase + ((((mh) << 6) + 32 + lr) << 6) + swk1];       \
  A6 = *(const u16x8*)&As[c][wrbase + ((((mh) << 6) + 48 + lr) << 6) + swk0];       \
  A7 = *(const u16x8*)&As[c][wrbase + ((((mh) << 6) + 48 + lr) << 6) + swk1]

#define RDB(c, nh, V00, V01, V10, V11)                                                   \
  V00 = *(const u16x8*)&Bs[c][wcbase + ((brow0 + (((nh) << 1) + 0) * 16 + lr) << 6) + swk0]; \
  V01 = *(const u16x8*)&Bs[c][wcbase + ((brow0 + (((nh) << 1) + 0) * 16 + lr) << 6) + swk1]; \
  V10 = *(const u16x8*)&Bs[c][wcbase + ((brow0 + (((nh) << 1) + 1) * 16 + lr) << 6) + swk0]; \
  V11 = *(const u16x8*)&Bs[c][wcbase + ((brow0 + (((nh) << 1) + 1) * 16 + lr) << 6) + swk1]

#define QM(mh, nh, V00, V01, V10, V11)                \
  mfma16(acc[((mh) << 2) + 0][((nh) << 1) + 0], A0, V00); \
  mfma16(acc[((mh) << 2) + 0][((nh) << 1) + 1], A0, V10); \
  mfma16(acc[((mh) << 2) + 1][((nh) << 1) + 0], A2, V00); \
  mfma16(acc[((mh) << 2) + 1][((nh) << 1) + 1], A2, V10); \
  mfma16(acc[((mh) << 2) + 2][((nh) << 1) + 0], A4, V00); \
  mfma16(acc[((mh) << 2) + 2][((nh) << 1) + 1], A4, V10); \
  mfma16(acc[((mh) << 2) + 3][((nh) << 1) + 0], A6, V00); \
  mfma16(acc[((mh) << 2) + 3][((nh) << 1) + 1], A6, V10); \
  mfma16(acc[((mh) << 2) + 0][((nh) << 1) + 0], A1, V01); \
  mfma16(acc[((mh) << 2) + 0][((nh) << 1) + 1], A1, V11); \
  mfma16(acc[((mh) << 2) + 1][((nh) << 1) + 0], A3, V01); \
  mfma16(acc[((mh) << 2) + 1][((nh) << 1) + 1], A3, V11); \
  mfma16(acc[((mh) << 2) + 2][((nh) << 1) + 0], A5, V01); \
  mfma16(acc[((mh) << 2) + 2][((nh) << 1) + 1], A5, V11); \
  mfma16(acc[((mh) << 2) + 3][((nh) << 1) + 0], A7, V01); \
  mfma16(acc[((mh) << 2) + 3][((nh) << 1) + 1], A7, V11)

template <int RELU>
__global__ __launch_bounds__(512, 1) void gemm256(const u16* __restrict__ A,
                                                  const u16* __restrict__ Bt,
                                                  const float* __restrict__ bias,
                                                  u16* __restrict__ C, int M, int N, int K) {
  __shared__ __align__(16) u16 As[2][16384];
  __shared__ __align__(16) u16 Bs[2][16384];
  const int nbn = N >> 8;
  const int cpx = gridDim.x >> 3;
  const int bid = blockIdx.x;
  const int wgid = (bid & 7) * cpx + (bid >> 3);
  const int bm = wgid / nbn, bn = wgid - bm * nbn;
  const int tid = threadIdx.x;
  const int wid = tid >> 6, lane = tid & 63;
  const int wr = wid >> 2, wc = wid & 3;
  const int lr = lane & 15, kg0 = lane >> 4;
  const int swk0 = ((kg0 ^ (lr & 7)) << 3);
  const int swk1 = (((kg0 + 4) ^ (lr & 7)) << 3);
  const int wrbase = wr << 13;
  const int wcbase = (wc >> 1) << 13;
  const int brow0 = (wc & 1) << 6;
  const int rowinc = tid >> 3;
  const int gcol = (((tid & 7) ^ (rowinc & 7)) << 3);
  const u16* Ag = A + (size_t)((bm << 8) + rowinc) * K + gcol;
  const u16* Bg = Bt + (size_t)((bn << 8) + rowinc) * K + gcol;
  const int ldsw = wid << 9;

  f32x4 acc[8][4];
  const f32x4 zero = {0.f, 0.f, 0.f, 0.f};
#pragma unroll
  for (int m = 0; m < 8; ++m)
#pragma unroll
    for (int n = 0; n < 4; ++n) acc[m][n] = zero;

  u16x8 A0, A1, A2, A3, A4, A5, A6, A7;
  u16x8 B00, B01, B10, B11;
  u16x8 C00, C01, C10, C11;

  auto stgA = [&](int c, int h, int koff) {
    gload16(Ag + (size_t)(h << 7) * K + koff, &As[c][(h << 13) + ldsw]);
    gload16(Ag + (size_t)((h << 7) + 64) * K + koff, &As[c][(h << 13) + 4096 + ldsw]);
  };
  auto stgB = [&](int c, int h, int koff) {
    gload16(Bg + (size_t)(h << 7) * K + koff, &Bs[c][(h << 13) + ldsw]);
    gload16(Bg + (size_t)((h << 7) + 64) * K + koff, &Bs[c][(h << 13) + 4096 + ldsw]);
  };

  stgA(0, 0, 0); stgA(0, 1, 0); stgB(0, 0, 0); stgB(0, 1, 0);
  stgB(1, 0, 64); stgB(1, 1, 64);
  VM(4);
  BAR();

  const int niter = K >> 7;
  int k1 = 64, k2 = 128, k3 = 192;
#pragma unroll 1
  for (int i = 0; i < niter - 1; ++i) {
    RDA(0, 0); RDB(0, 0, B00, B01, B10, B11); stgA(1, 0, k1);
    PRIO1(); QM(0, 0, B00, B01, B10, B11); PRIO0();
    RDB(0, 1, C00, C01, C10, C11); stgA(1, 1, k1);
    PRIO1(); QM(0, 1, C00, C01, C10, C11); PRIO0(); BAR();
    RDA(0, 1); stgB(0, 0, k2);
    PRIO1(); QM(1, 1, C00, C01, C10, C11); PRIO0();
    stgB(0, 1, k2);
    PRIO1(); QM(1, 0, B00, B01, B10, B11); PRIO0(); VM(4); BAR();
    RDA(1, 0); RDB(1, 0, B00, B01, B10, B11); stgA(0, 0, k2);
    PRIO1(); QM(0, 0, B00, B01, B10, B11); PRIO0();
    RDB(1, 1, C00, C01, C10, C11); stgA(0, 1, k2);
    PRIO1(); QM(0, 1, C00, C01, C10, C11); PRIO0(); BAR();
    RDA(1, 1); stgB(1, 0, k3);
    PRIO1(); QM(1, 1, C00, C01, C10, C11); PRIO0();
    stgB(1, 1, k3);
    PRIO1(); QM(1, 0, B00, B01, B10, B11); PRIO0(); VM(4); BAR();
    k1 += 128; k2 += 128; k3 += 128;
  }
  RDA(0, 0); RDB(0, 0, B00, B01, B10, B11); stgA(1, 0, k1);
  PRIO1(); QM(0, 0, B00, B01, B10, B11); PRIO0();
  RDB(0, 1, C00, C01, C10, C11); stgA(1, 1, k1);
  PRIO1(); QM(0, 1, C00, C01, C10, C11); PRIO0(); BAR();
  RDA(0, 1);
  PRIO1(); QM(1, 1, C00, C01, C10, C11); PRIO0();
  PRIO1(); QM(1, 0, B00, B01, B10, B11); PRIO0(); VM(0); BAR();
  RDA(1, 0); RDB(1, 0, B00, B01, B10, B11);
  PRIO1(); QM(0, 0, B00, B01, B10, B11); PRIO0();
  RDB(1, 1, C00, C01, C10, C11);
  PRIO1(); QM(0, 1, C00, C01, C10, C11); PRIO0(); BAR();
  RDA(1, 1);
  PRIO1(); QM(1, 1, C00, C01, C10, C11); PRIO0();
  PRIO1(); QM(1, 0, B00, B01, B10, B11); PRIO0();

  const int r0 = kg0 << 2;
  const int cc = lr;
#pragma unroll
  for (int m8 = 0; m8 < 8; ++m8) {
    const size_t grow = (size_t)((bm << 8) + (wr << 7) + (m8 << 4) + r0);
#pragma unroll
    for (int n4 = 0; n4 < 4; ++n4) {
      const int gc = (bn << 8) + (wc << 6) + (n4 << 4) + cc;
      const float bv = bias[gc];
#pragma unroll
      for (int rr = 0; rr < 4; ++rr) {
        float v = acc[m8][n4][rr] + bv;
        if (RELU) v = fmaxf(v, 0.f);
        C[(grow + rr) * (size_t)N + gc] = f2b(v);
      }
    }
  }
}

// ---------------- attention: per-wave (b,h); qkv [NTOK][1536] ----------------
// SEL=0: ctx[NTOK][512] (all rows). SEL=1: ctx_sel[b][512] (only row s == b&7).
template <int SEL>
__global__ __launch_bounds__(256) void attn_kernel(const u16* __restrict__ QKV,
                                                   u16* __restrict__ ctx) {
  __shared__ __align__(16) u16 sm[4][3][8][72];
  __shared__ float at[4][8][8];
  const int tid = threadIdx.x;
  const int wid = tid >> 6, lane = tid & 63;
  const int bh = blockIdx.x * 4 + wid;
  const int b = bh >> 3, h = bh & 7;
  const int s = lane >> 3, g = lane & 7;
  const u16* base = QKV + (size_t)(b * 8 + s) * 1536 + h * 64 + g * 8;
#pragma unroll
  for (int t = 0; t < 3; ++t)
    *(u16x8*)&sm[wid][t][s][g * 8] = *(const u16x8*)(base + t * 512);
  __syncthreads();
  float sc = 0.f;
#pragma unroll
  for (int c = 0; c < 8; ++c) {
    const int cg = ((c + g) & 7) * 8;
    u16x8 qv = *(const u16x8*)&sm[wid][0][s][cg];
    u16x8 kv = *(const u16x8*)&sm[wid][1][g][cg];
#pragma unroll
    for (int e = 0; e < 8; ++e) sc += b2f(qv[e]) * b2f(kv[e]);
  }
  sc *= 0.125f;
  float mx = fmaxf(sc, __shfl_xor(sc, 1));
  mx = fmaxf(mx, __shfl_xor(mx, 2));
  mx = fmaxf(mx, __shfl_xor(mx, 4));
  const float ex = __expf(sc - mx);
  float sum = ex;
  sum += __shfl_xor(sum, 1);
  sum += __shfl_xor(sum, 2);
  sum += __shfl_xor(sum, 4);
  at[wid][s][g] = ex / sum;
  __syncthreads();
  float o[8] = {0.f, 0.f, 0.f, 0.f, 0.f, 0.f, 0.f, 0.f};
#pragma unroll
  for (int j = 0; j < 8; ++j) {
    const float a = at[wid][s][j];
    u16x8 vv = *(const u16x8*)&sm[wid][2][j][g * 8];
#pragma unroll
    for (int e = 0; e < 8; ++e) o[e] += a * b2f(vv[e]);
  }
  u16x8 ov;
#pragma unroll
  for (int e = 0; e < 8; ++e) ov[e] = f2b(o[e]);
  if (SEL) {
    if (s == (b & 7))
      *(u16x8*)(ctx + (size_t)b * 512 + h * 64 + g * 8) = ov;
  } else {
    *(u16x8*)(ctx + (size_t)(b * 8 + s) * 512 + h * 64 + g * 8) = ov;
  }
}

// ---------------- LayerNorm(tmp + h) -> h (in place, full rows) ----------------
__global__ __launch_bounds__(256) void ln_kernel(const u16* __restrict__ t,
                                                 u16* __restrict__ h,
                                                 const float* __restrict__ gam,
                                                 const float* __restrict__ bet) {
  const int tid = threadIdx.x;
  const int wid = tid >> 6, lane = tid & 63;
  const int row = blockIdx.x * 4 + wid;
  const size_t base = (size_t)row * 512 + lane * 8;
  u16x8 tv = *(const u16x8*)(t + base);
  u16x8 hv = *(const u16x8*)(h + base);
  float x[8];
  float s1 = 0.f, s2 = 0.f;
#pragma unroll
  for (int e = 0; e < 8; ++e) {
    x[e] = b2f(tv[e]) + b2f(hv[e]);
    s1 += x[e];
    s2 += x[e] * x[e];
  }
#pragma unroll
  for (int m = 1; m < 64; m <<= 1) {
    s1 += __shfl_xor(s1, m);
    s2 += __shfl_xor(s2, m);
  }
  const float mu = s1 * (1.f / 512.f);
  const float var = s2 * (1.f / 512.f) - mu * mu;
  const float rs = rsqrtf(var + 1e-6f);
  const float4 g0 = *(const float4*)(gam + lane * 8);
  const float4 g1 = *(const float4*)(gam + lane * 8 + 4);
  const float4 b0 = *(const float4*)(bet + lane * 8);
  const float4 b1 = *(const float4*)(bet + lane * 8 + 4);
  const float gv[8] = {g0.x, g0.y, g0.z, g0.w, g1.x, g1.y, g1.z, g1.w};
  const float bv[8] = {b0.x, b0.y, b0.z, b0.w, b1.x, b1.y, b1.z, b1.w};
  u16x8 yv;
#pragma unroll
  for (int e = 0; e < 8; ++e) yv[e] = f2b((x[e] - mu) * rs * gv[e] + bv[e]);
  *(u16x8*)(h + base) = yv;
}

// ---- layer-2 LN1: h_sel[b] = LN(tmp_sel[b] + h[8b + (b&7)]) ----
__global__ __launch_bounds__(256) void ln_gather_kernel(const u16* __restrict__ t,
                                                        const u16* __restrict__ h,
                                                        u16* __restrict__ hsel,
                                                        const float* __restrict__ gam,
                                                        const float* __restrict__ bet) {
  const int tid = threadIdx.x;
  const int wid = tid >> 6, lane = tid & 63;
  const int b = blockIdx.x * 4 + wid;
  const size_t tb = (size_t)(b * 8 + (b & 7));
  u16x8 tv = *(const u16x8*)(t + (size_t)b * 512 + lane * 8);
  u16x8 hv = *(const u16x8*)(h + tb * 512 + lane * 8);
  float x[8];
  float s1 = 0.f, s2 = 0.f;
#pragma unroll
  for (int e = 0; e < 8; ++e) {
    x[e] = b2f(tv[e]) + b2f(hv[e]);
    s1 += x[e];
    s2 += x[e] * x[e];
  }
#pragma unroll
  for (int m = 1; m < 64; m <<= 1) {
    s1 += __shfl_xor(s1, m);
    s2 += __shfl_xor(s2, m);
  }
  const float mu = s1 * (1.f / 512.f);
  const float var = s2 * (1.f / 512.f) - mu * mu;
  const float rs = rsqrtf(var + 1e-6f);
  const float4 g0 = *(const float4*)(gam + lane * 8);
  const float4 g1 = *(const float4*)(gam + lane * 8 + 4);
  const float4 b0 = *(const float4*)(bet + lane * 8);
  const float4 b1 = *(const float4*)(bet + lane * 8 + 4);
  const float gv[8] = {g0.x, g0.y, g0.z, g0.w, g1.x, g1.y, g1.z, g1.w};
  const float bv[8] = {b0.x, b0.y, b0.z, b0.w, b1.x, b1.y, b1.z, b1.w};
  u16x8 yv;
#pragma unroll
  for (int e = 0; e < 8; ++e) yv[e] = f2b((x[e] - mu) * rs * gv[e] + bv[e]);
  *(u16x8*)(hsel + (size_t)b * 512 + lane * 8) = yv;
}

// ---- layer-2 LN2 + output: out[b] = LN(tmp_sel[b] + h_sel[b]) (fp32) ----
__global__ __launch_bounds__(256) void ln_final_kernel(const u16* __restrict__ t,
                                                       const u16* __restrict__ hsel,
                                                       const float* __restrict__ gam,
                                                       const float* __restrict__ bet,
                                                       float* __restrict__ out) {
  const int tid = threadIdx.x;
  const int wid = tid >> 6, lane = tid & 63;
  const int b = blockIdx.x * 4 + wid;
  const size_t base = (size_t)b * 512 + lane * 8;
  u16x8 tv = *(const u16x8*)(t + base);
  u16x8 hv = *(const u16x8*)(hsel + base);
  float x[8];
  float s1 = 0.f, s2 = 0.f;
#pragma unroll
  for (int e = 0; e < 8; ++e) {
    x[e] = b2f(tv[e]) + b2f(hv[e]);
    s1 += x[e];
    s2 += x[e] * x[e];
  }
#pragma unroll
  for (int m = 1; m < 64; m <<= 1) {
    s1 += __shfl_xor(s1, m);
    s2 += __shfl_xor(s2, m);
  }
  const float mu = s1 * (1.f / 512.f);
  const float var = s2 * (1.f / 512.f) - mu * mu;
  const float rs = rsqrtf(var + 1e-6f);
  const float4 g0 = *(const float4*)(gam + lane * 8);
  const float4 g1 = *(const float4*)(gam + lane * 8 + 4);
  const float4 b0 = *(const float4*)(bet + lane * 8);
  const float4 b1 = *(const float4*)(bet + lane * 8 + 4);
  const float gv[8] = {g0.x, g0.y, g0.z, g0.w, g1.x, g1.y, g1.z, g1.w};
  const float bv[8] = {b0.x, b0.y, b0.z, b0.w, b1.x, b1.y, b1.z, b1.w};
  float y[8];
#pragma unroll
  for (int e = 0; e < 8; ++e) y[e] = (x[e] - mu) * rs * gv[e] + bv[e];
  float4* op = (float4*)(out + base);
  op[0] = make_float4(y[0], y[1], y[2], y[3]);
  op[1] = make_float4(y[4], y[5], y[6], y[7]);
}

static void launch_gemm(const u16* A, const u16* Bt, const float* bias, u16* C, int M, int N,
                        int K, int relu, hipStream_t st) {
  dim3 grid((M >> 8) * (N >> 8));
  if (relu)
    gemm256<1><<<grid, 512, 0, st>>>(A, Bt, bias, C, M, N, K);
  else
    gemm256<0><<<grid, 512, 0, st>>>(A, Bt, bias, C, M, N, K);
}

extern "C" void kernel_launch(void* const* d_in, const int* in_sizes, int n_in, void* d_out,
                              int out_size, void* d_ws, size_t ws_size, hipStream_t stream) {
  const float* x = (const float*)d_in[0];
  const float* Wq = (const float*)d_in[1];
  const float* bq = (const float*)d_in[2];
  const float* Wk = (const float*)d_in[3];
  const float* bk = (const float*)d_in[4];
  const float* Wv = (const float*)d_in[5];
  const float* bv = (const float*)d_in[6];
  const float* Wo = (const float*)d_in[7];
  const float* bo = (const float*)d_in[8];
  const float* ln1g = (const float*)d_in[9];
  const float* ln1b = (const float*)d_in[10];
  const float* W1 = (const float*)d_in[11];
  const float* b1 = (const float*)d_in[12];
  const float* W2 = (const float*)d_in[13];
  const float* b2 = (const float*)d_in[14];
  const float* ln2g = (const float*)d_in[15];
  const float* ln2b = (const float*)d_in[16];
  float* out = (float*)d_out;

  char* ws = (char*)d_ws;
  const size_t o_tab = 0;
  const size_t o_bqkv = 16384;
  const size_t o_w = 28672;
  const size_t o_h = o_w + 12582912;
  const size_t o_buf = o_h + (size_t)NTOK * 512 * 2;
  const size_t o_tmp = o_buf + (size_t)NTOK * 2048 * 2;
  const size_t o_hsel = o_tmp + (size_t)NTOK * 512 * 2;
  const size_t need = o_hsel + (size_t)NSEL * 512 * 2;
  if (ws_size < need) return;

  float* tab = (float*)(ws + o_tab);
  float* bqkv = (float*)(ws + o_bqkv);
  u16* wbf = (u16*)(ws + o_w);
  u16* h = (u16*)(ws + o_h);
  u16* buf = (u16*)(ws + o_buf);
  u16* ctx = buf + (size_t)NTOK * 1536;
  u16* tmp = (u16*)(ws + o_tmp);
  u16* hsel = (u16*)(ws + o_hsel);

  table_kernel<<<16, 256, 0, stream>>>(tab);
  biaspack_kernel<<<12, 256, 0, stream>>>(bq, bk, bv, bqkv);

  TJobs jobs;
  int blk = 0, nj = 0;
  auto add = [&](const float* s, u16* dmat, int Ki, int Ni) {
    jobs.j[nj].src = s;
    jobs.j[nj].dst = dmat;
    jobs.j[nj].Ki = Ki;
    jobs.j[nj].Ni = Ni;
    jobs.j[nj].blk0 = blk;
    ++nj;
    blk += (Ki / 64) * (Ni / 64);
  };
  for (int l = 0; l < 2; ++l) {
    u16* wl = wbf + (size_t)l * 3145728;
    add(Wq + (size_t)l * 262144, wl, 512, 512);
    add(Wk + (size_t)l * 262144, wl + 262144, 512, 512);
    add(Wv + (size_t)l * 262144, wl + 524288, 512, 512);
    add(Wo + (size_t)l * 262144, wl + 786432, 512, 512);
    add(W1 + (size_t)l * 1048576, wl + 1048576, 512, 2048);
    add(W2 + (size_t)l * 1048576, wl + 2097152, 2048, 512);
  }
  wconv_kernel<<<blk, 256, 0, stream>>>(jobs);
  posenc_kernel<<<32768, 256, 0, stream>>>(x, tab, h);

  // ---------------- layer 0: full computation ----------------
  {
    u16* wl = wbf;
    launch_gemm(h, wl, bqkv, buf, NTOK, 1536, 512, 0, stream);
    attn_kernel<0><<<32768, 256, 0, stream>>>(buf, ctx);
    launch_gemm(ctx, wl + 786432, bo, tmp, NTOK, 512, 512, 0, stream);
    ln_kernel<<<32768, 256, 0, stream>>>(tmp, h, ln1g, ln1b);
    launch_gemm(h, wl + 1048576, b1, buf, NTOK, 2048, 512, 1, stream);
    launch_gemm(buf, wl + 2097152, b2, tmp, NTOK, 512, 2048, 0, stream);
    ln_kernel<<<32768, 256, 0, stream>>>(tmp, h, ln2g, ln2b);
  }

  // ---------------- layer 1: only selected tokens past attention ----------------
  {
    u16* wl = wbf + 3145728;
    u16* ctx_sel = ctx;     // [NSEL][512]
    u16* tmp_sel = tmp;     // [NSEL][512]
    u16* hid_sel = buf;     // [NSEL][2048] (qkv no longer needed after attn)
    // full QKV (attention needs K,V of all tokens)
    launch_gemm(h, wl, bqkv + 1536, buf, NTOK, 1536, 512, 0, stream);
    // attention, writing only the selected row per (b, head)
    attn_kernel<1><<<32768, 256, 0, stream>>>(buf, ctx_sel);
    // O-projection on selected tokens
    launch_gemm(ctx_sel, wl + 786432, bo + 512, tmp_sel, NSEL, 512, 512, 0, stream);
    // LN1 with gathered residual: h_sel = LN(tmp_sel + h[t(b)])
    ln_gather_kernel<<<NSEL / 4, 256, 0, stream>>>(tmp_sel, h, hsel, ln1g + 512, ln1b + 512);
    // FFN1 (+ReLU) on selected
    launch_gemm(hsel, wl + 1048576, b1 + 2048, hid_sel, NSEL, 2048, 512, 1, stream);
    // FFN2 on selected
    launch_gemm(hid_sel, wl + 2097152, b2 + 512, tmp_sel, NSEL, 512, 2048, 0, stream);
    // LN2 + fp32 output
    ln_final_kernel<<<NSEL / 4, 256, 0, stream>>>(tmp_sel, hsel, ln2g + 512, ln2b + 512, out);
  }
}

// Round 12
// 1635.241 us; speedup vs baseline: 1.7452x; 1.0437x over previous
//
#include <hip/hip_runtime.h>

typedef unsigned short u16;
typedef unsigned int u32;
typedef __attribute__((ext_vector_type(8))) unsigned short u16x8;
typedef __attribute__((ext_vector_type(4))) float f32x4;

#define NTOK 131072  // 16384 * 8 tokens
#define NSEL 16384   // selected tokens (one per batch)

__device__ __forceinline__ float b2f(u16 v) {
  return __uint_as_float(((u32)v) << 16);
}
__device__ __forceinline__ u16 f2b(float f) {
  u32 u = __float_as_uint(f);
  u32 r = u + 0x7fffu + ((u >> 16) & 1u);
  return (u16)(r >> 16);
}

__device__ __forceinline__ void gload16(const void* g, void* l) {
  __builtin_amdgcn_global_load_lds((const __attribute__((address_space(1))) void*)g,
                                   (__attribute__((address_space(3))) void*)l, 16, 0, 0);
}

__device__ __forceinline__ void mfma16(f32x4& c, u16x8 a, u16x8 b) {
  asm("v_mfma_f32_16x16x32_bf16 %0, %1, %2, %0" : "+v"(c) : "v"(a), "v"(b));
}

#define BAR() __builtin_amdgcn_s_barrier()
#define VM(n) asm volatile("s_waitcnt vmcnt(" #n ")" ::: "memory")
#define PRIO1() __builtin_amdgcn_s_setprio(1)
#define PRIO0() __builtin_amdgcn_s_setprio(0)

// ---------------- sinusoid table [8][512] ----------------
__global__ __launch_bounds__(256) void table_kernel(float* __restrict__ tab) {
  const int i = blockIdx.x * 256 + threadIdx.x;
  if (i >= 4096) return;
  const int p = i >> 9, j = i & 511;
  const float ex = 2.f * (float)(j >> 1) / 512.f;
  const float ang = (float)p * powf(10000.f, -ex);
  tab[i] = (j & 1) ? cosf(ang) : sinf(ang);
}

// ---------------- pack bq|bk|bv -> [L][1536] ----------------
__global__ __launch_bounds__(256) void biaspack_kernel(const float* __restrict__ bq,
                                                       const float* __restrict__ bk,
                                                       const float* __restrict__ bv,
                                                       float* __restrict__ dst) {
  const int i = blockIdx.x * 256 + threadIdx.x;
  if (i >= 3072) return;
  const int l = i / 1536, j = i % 1536;
  float v;
  if (j < 512) v = bq[l * 512 + j];
  else if (j < 1024) v = bk[l * 512 + j - 512];
  else v = bv[l * 512 + j - 1024];
  dst[i] = v;
}

// ---------------- weight transpose+convert fp32[K][N] -> bf16[N][K] ----------------
struct TJob { const float* src; u16* dst; int Ki, Ni, blk0; };
struct TJobs { TJob j[12]; };

__global__ __launch_bounds__(256) void wconv_kernel(TJobs jobs) {
  __shared__ float tile[64][65];
  const int bid = blockIdx.x;
  int ji = 0;
#pragma unroll
  for (int t = 1; t < 12; ++t)
    if (bid >= jobs.j[t].blk0) ji = t;
  const TJob J = jobs.j[ji];
  const int rel = bid - J.blk0;
  const int ntn = J.Ni >> 6;
  const int tk = rel / ntn, tn = rel % ntn;
  const int tid = threadIdx.x;
  const int cn = tid & 63, rk = tid >> 6;
#pragma unroll
  for (int r = 0; r < 16; ++r) {
    const int kk = rk + r * 4;
    tile[kk][cn] = J.src[(size_t)(tk * 64 + kk) * J.Ni + tn * 64 + cn];
  }
  __syncthreads();
  const int ck = tid & 63, rn = tid >> 6;
#pragma unroll
  for (int r = 0; r < 16; ++r) {
    const int nn = rn + r * 4;
    J.dst[(size_t)(tn * 64 + nn) * J.Ki + tk * 64 + ck] = f2b(tile[ck][nn]);
  }
}

// ---------------- posenc: h_bf16 = x_fp32 + tab[s][:] ----------------
__global__ __launch_bounds__(256) void posenc_kernel(const float* __restrict__ x,
                                                     const float* __restrict__ tab,
                                                     u16* __restrict__ h) {
  const int i = blockIdx.x * 256 + threadIdx.x;
  const size_t e0 = (size_t)i * 8;
  const int d = (int)(e0 & 511);
  const int srow = (int)((e0 >> 9) & 7);
  const float4 a0 = *(const float4*)(x + e0);
  const float4 a1 = *(const float4*)(x + e0 + 4);
  const float* tp = tab + srow * 512 + d;
  float v[8] = {a0.x, a0.y, a0.z, a0.w, a1.x, a1.y, a1.z, a1.w};
  u16x8 o;
#pragma unroll
  for (int e = 0; e < 8; ++e) o[e] = f2b(v[e] + tp[e]);
  *(u16x8*)(h + e0) = o;
}

// ================== GEMM 256x256 (round-6 config): 4-window K-loop ==================
#define RDA(c, mh)                                                                  \
  A0 = *(const u16x8*)&As[c][wrbase + ((((mh) << 6) + 0 + lr) << 6) + swk0];        \
  A1 = *(const u16x8*)&As[c][wrbase + ((((mh) << 6) + 0 + lr) << 6) + swk1];        \
  A2 = *(const u16x8*)&As[c][wrbase + ((((mh) << 6) + 16 + lr) << 6) + swk0];       \
  A3 = *(const u16x8*)&As[c][wrbase + ((((mh) << 6) + 16 + lr) << 6) + swk1];       \
  A4 = *(const u16x8*)&As[c][wrbase + ((((mh) << 6) + 32 + lr) << 6) + swk0];       \
  A5 = *(const u16x8*)&As[c][wrbase + ((((mh) << 6) + 32 + lr) << 6) + swk1];       \
  A6 = *(const u16x8*)&As[c][wrbase + ((((mh) << 6) + 48 + lr) << 6) + swk0];       \
  A7 = *(const u16x8*)&As[c][wrbase + ((((mh) << 6) + 48 + lr) << 6) + swk1]

#define RDB(c, nh, V00, V01, V10, V11)                                                   \
  V00 = *(const u16x8*)&Bs[c][wcbase + ((brow0 + (((nh) << 1) + 0) * 16 + lr) << 6) + swk0]; \
  V01 = *(const u16x8*)&Bs[c][wcbase + ((brow0 + (((nh) << 1) + 0) * 16 + lr) << 6) + swk1]; \
  V10 = *(const u16x8*)&Bs[c][wcbase + ((brow0 + (((nh) << 1) + 1) * 16 + lr) << 6) + swk0]; \
  V11 = *(const u16x8*)&Bs[c][wcbase + ((brow0 + (((nh) << 1) + 1) * 16 + lr) << 6) + swk1]

#define QM(mh, nh, V00, V01, V10, V11)                \
  mfma16(acc[((mh) << 2) + 0][((nh) << 1) + 0], A0, V00); \
  mfma16(acc[((mh) << 2) + 0][((nh) << 1) + 1], A0, V10); \
  mfma16(acc[((mh) << 2) + 1][((nh) << 1) + 0], A2, V00); \
  mfma16(acc[((mh) << 2) + 1][((nh) << 1) + 1], A2, V10); \
  mfma16(acc[((mh) << 2) + 2][((nh) << 1) + 0], A4, V00); \
  mfma16(acc[((mh) << 2) + 2][((nh) << 1) + 1], A4, V10); \
  mfma16(acc[((mh) << 2) + 3][((nh) << 1) + 0], A6, V00); \
  mfma16(acc[((mh) << 2) + 3][((nh) << 1) + 1], A6, V10); \
  mfma16(acc[((mh) << 2) + 0][((nh) << 1) + 0], A1, V01); \
  mfma16(acc[((mh) << 2) + 0][((nh) << 1) + 1], A1, V11); \
  mfma16(acc[((mh) << 2) + 1][((nh) << 1) + 0], A3, V01); \
  mfma16(acc[((mh) << 2) + 1][((nh) << 1) + 1], A3, V11); \
  mfma16(acc[((mh) << 2) + 2][((nh) << 1) + 0], A5, V01); \
  mfma16(acc[((mh) << 2) + 2][((nh) << 1) + 1], A5, V11); \
  mfma16(acc[((mh) << 2) + 3][((nh) << 1) + 0], A7, V01); \
  mfma16(acc[((mh) << 2) + 3][((nh) << 1) + 1], A7, V11)

template <int RELU>
__global__ __launch_bounds__(512, 1) void gemm256(const u16* __restrict__ A,
                                                  const u16* __restrict__ Bt,
                                                  const float* __restrict__ bias,
                                                  u16* __restrict__ C, int M, int N, int K) {
  __shared__ __align__(16) u16 As[2][16384];
  __shared__ __align__(16) u16 Bs[2][16384];
  const int nbn = N >> 8;
  const int cpx = gridDim.x >> 3;
  const int bid = blockIdx.x;
  const int wgid = (bid & 7) * cpx + (bid >> 3);
  const int bm = wgid / nbn, bn = wgid - bm * nbn;
  const int tid = threadIdx.x;
  const int wid = tid >> 6, lane = tid & 63;
  const int wr = wid >> 2, wc = wid & 3;
  const int lr = lane & 15, kg0 = lane >> 4;
  const int swk0 = ((kg0 ^ (lr & 7)) << 3);
  const int swk1 = (((kg0 + 4) ^ (lr & 7)) << 3);
  const int wrbase = wr << 13;
  const int wcbase = (wc >> 1) << 13;
  const int brow0 = (wc & 1) << 6;
  const int rowinc = tid >> 3;
  const int gcol = (((tid & 7) ^ (rowinc & 7)) << 3);
  const u16* Ag = A + (size_t)((bm << 8) + rowinc) * K + gcol;
  const u16* Bg = Bt + (size_t)((bn << 8) + rowinc) * K + gcol;
  const int ldsw = wid << 9;

  f32x4 acc[8][4];
  const f32x4 zero = {0.f, 0.f, 0.f, 0.f};
#pragma unroll
  for (int m = 0; m < 8; ++m)
#pragma unroll
    for (int n = 0; n < 4; ++n) acc[m][n] = zero;

  u16x8 A0, A1, A2, A3, A4, A5, A6, A7;
  u16x8 B00, B01, B10, B11;
  u16x8 C00, C01, C10, C11;

  auto stgA = [&](int c, int h, int koff) {
    gload16(Ag + (size_t)(h << 7) * K + koff, &As[c][(h << 13) + ldsw]);
    gload16(Ag + (size_t)((h << 7) + 64) * K + koff, &As[c][(h << 13) + 4096 + ldsw]);
  };
  auto stgB = [&](int c, int h, int koff) {
    gload16(Bg + (size_t)(h << 7) * K + koff, &Bs[c][(h << 13) + ldsw]);
    gload16(Bg + (size_t)((h << 7) + 64) * K + koff, &Bs[c][(h << 13) + 4096 + ldsw]);
  };

  stgA(0, 0, 0); stgA(0, 1, 0); stgB(0, 0, 0); stgB(0, 1, 0);
  stgB(1, 0, 64); stgB(1, 1, 64);
  VM(4);
  BAR();

  const int niter = K >> 7;
  int k1 = 64, k2 = 128, k3 = 192;
#pragma unroll 1
  for (int i = 0; i < niter - 1; ++i) {
    RDA(0, 0); RDB(0, 0, B00, B01, B10, B11); stgA(1, 0, k1);
    PRIO1(); QM(0, 0, B00, B01, B10, B11); PRIO0();
    RDB(0, 1, C00, C01, C10, C11); stgA(1, 1, k1);
    PRIO1(); QM(0, 1, C00, C01, C10, C11); PRIO0(); BAR();
    RDA(0, 1); stgB(0, 0, k2);
    PRIO1(); QM(1, 1, C00, C01, C10, C11); PRIO0();
    stgB(0, 1, k2);
    PRIO1(); QM(1, 0, B00, B01, B10, B11); PRIO0(); VM(4); BAR();
    RDA(1, 0); RDB(1, 0, B00, B01, B10, B11); stgA(0, 0, k2);
    PRIO1(); QM(0, 0, B00, B01, B10, B11); PRIO0();
    RDB(1, 1, C00, C01, C10, C11); stgA(0, 1, k2);
    PRIO1(); QM(0, 1, C00, C01, C10, C11); PRIO0(); BAR();
    RDA(1, 1); stgB(1, 0, k3);
    PRIO1(); QM(1, 1, C00, C01, C10, C11); PRIO0();
    stgB(1, 1, k3);
    PRIO1(); QM(1, 0, B00, B01, B10, B11); PRIO0(); VM(4); BAR();
    k1 += 128; k2 += 128; k3 += 128;
  }
  RDA(0, 0); RDB(0, 0, B00, B01, B10, B11); stgA(1, 0, k1);
  PRIO1(); QM(0, 0, B00, B01, B10, B11); PRIO0();
  RDB(0, 1, C00, C01, C10, C11); stgA(1, 1, k1);
  PRIO1(); QM(0, 1, C00, C01, C10, C11); PRIO0(); BAR();
  RDA(0, 1);
  PRIO1(); QM(1, 1, C00, C01, C10, C11); PRIO0();
  PRIO1(); QM(1, 0, B00, B01, B10, B11); PRIO0(); VM(0); BAR();
  RDA(1, 0); RDB(1, 0, B00, B01, B10, B11);
  PRIO1(); QM(0, 0, B00, B01, B10, B11); PRIO0();
  RDB(1, 1, C00, C01, C10, C11);
  PRIO1(); QM(0, 1, C00, C01, C10, C11); PRIO0(); BAR();
  RDA(1, 1);
  PRIO1(); QM(1, 1, C00, C01, C10, C11); PRIO0();
  PRIO1(); QM(1, 0, B00, B01, B10, B11); PRIO0();

  const int r0 = kg0 << 2;
  const int cc = lr;
#pragma unroll
  for (int m8 = 0; m8 < 8; ++m8) {
    const size_t grow = (size_t)((bm << 8) + (wr << 7) + (m8 << 4) + r0);
#pragma unroll
    for (int n4 = 0; n4 < 4; ++n4) {
      const int gc = (bn << 8) + (wc << 6) + (n4 << 4) + cc;
      const float bv = bias[gc];
#pragma unroll
      for (int rr = 0; rr < 4; ++rr) {
        float v = acc[m8][n4][rr] + bv;
        if (RELU) v = fmaxf(v, 0.f);
        C[(grow + rr) * (size_t)N + gc] = f2b(v);
      }
    }
  }
}

// ---------------- layer-0 attention: per-wave (b,h); qkv [NTOK][1536] -> ctx [NTOK][512] ----------------
__global__ __launch_bounds__(256) void attn_kernel(const u16* __restrict__ QKV,
                                                   u16* __restrict__ ctx) {
  __shared__ __align__(16) u16 sm[4][3][8][72];
  __shared__ float at[4][8][8];
  const int tid = threadIdx.x;
  const int wid = tid >> 6, lane = tid & 63;
  const int bh = blockIdx.x * 4 + wid;
  const int b = bh >> 3, h = bh & 7;
  const int s = lane >> 3, g = lane & 7;
  const u16* base = QKV + (size_t)(b * 8 + s) * 1536 + h * 64 + g * 8;
#pragma unroll
  for (int t = 0; t < 3; ++t)
    *(u16x8*)&sm[wid][t][s][g * 8] = *(const u16x8*)(base + t * 512);
  __syncthreads();
  float sc = 0.f;
#pragma unroll
  for (int c = 0; c < 8; ++c) {
    const int cg = ((c + g) & 7) * 8;
    u16x8 qv = *(const u16x8*)&sm[wid][0][s][cg];
    u16x8 kv = *(const u16x8*)&sm[wid][1][g][cg];
#pragma unroll
    for (int e = 0; e < 8; ++e) sc += b2f(qv[e]) * b2f(kv[e]);
  }
  sc *= 0.125f;
  float mx = fmaxf(sc, __shfl_xor(sc, 1));
  mx = fmaxf(mx, __shfl_xor(mx, 2));
  mx = fmaxf(mx, __shfl_xor(mx, 4));
  const float ex = __expf(sc - mx);
  float sum = ex;
  sum += __shfl_xor(sum, 1);
  sum += __shfl_xor(sum, 2);
  sum += __shfl_xor(sum, 4);
  at[wid][s][g] = ex / sum;
  __syncthreads();
  float o[8] = {0.f, 0.f, 0.f, 0.f, 0.f, 0.f, 0.f, 0.f};
#pragma unroll
  for (int j = 0; j < 8; ++j) {
    const float a = at[wid][s][j];
    u16x8 vv = *(const u16x8*)&sm[wid][2][j][g * 8];
#pragma unroll
    for (int e = 0; e < 8; ++e) o[e] += a * b2f(vv[e]);
  }
  u16x8 ov;
#pragma unroll
  for (int e = 0; e < 8; ++e) ov[e] = f2b(o[e]);
  *(u16x8*)(ctx + (size_t)(b * 8 + s) * 512 + h * 64 + g * 8) = ov;
}

// ---------------- layer-1 attention (selected row only): KV [NTOK][1024], Qs [NSEL][512] ----------------
__global__ __launch_bounds__(256) void attn_sel_kernel(const u16* __restrict__ KV,
                                                       const u16* __restrict__ Qs,
                                                       u16* __restrict__ ctx) {
  __shared__ __align__(16) u16 sm[4][2][8][72];
  __shared__ float at[4][8];
  const int tid = threadIdx.x;
  const int wid = tid >> 6, lane = tid & 63;
  const int bh = blockIdx.x * 4 + wid;
  const int b = bh >> 3, h = bh & 7;
  const int s = lane >> 3, g = lane & 7;
  const u16* base = KV + (size_t)(b * 8 + s) * 1024 + h * 64 + g * 8;
  *(u16x8*)&sm[wid][0][s][g * 8] = *(const u16x8*)(base);        // K
  *(u16x8*)&sm[wid][1][s][g * 8] = *(const u16x8*)(base + 512);  // V
  const u16x8 qv = *(const u16x8*)(Qs + (size_t)b * 512 + h * 64 + g * 8);
  __syncthreads();
  // score for key s: partial over d-chunk g, reduce over g (lane bits 0..2)
  float p = 0.f;
  {
    u16x8 kv8 = *(const u16x8*)&sm[wid][0][s][g * 8];
#pragma unroll
    for (int e = 0; e < 8; ++e) p += b2f(qv[e]) * b2f(kv8[e]);
  }
  p += __shfl_xor(p, 1);
  p += __shfl_xor(p, 2);
  p += __shfl_xor(p, 4);
  p *= 0.125f;  // sc for key s (replicated across the 8 g-lanes)
  // softmax across the 8 keys (lane bits 3..5)
  float mx = fmaxf(p, __shfl_xor(p, 8));
  mx = fmaxf(mx, __shfl_xor(mx, 16));
  mx = fmaxf(mx, __shfl_xor(mx, 32));
  const float ex = __expf(p - mx);
  float sum = ex;
  sum += __shfl_xor(sum, 8);
  sum += __shfl_xor(sum, 16);
  sum += __shfl_xor(sum, 32);
  if (g == 0) at[wid][s] = ex / sum;
  __syncthreads();
  if (s == 0) {
    float o[8] = {0.f, 0.f, 0.f, 0.f, 0.f, 0.f, 0.f, 0.f};
#pragma unroll
    for (int j = 0; j < 8; ++j) {
      const float a = at[wid][j];
      u16x8 vv = *(const u16x8*)&sm[wid][1][j][g * 8];
#pragma unroll
      for (int e = 0; e < 8; ++e) o[e] += a * b2f(vv[e]);
    }
    u16x8 ov;
#pragma unroll
    for (int e = 0; e < 8; ++e) ov[e] = f2b(o[e]);
    *(u16x8*)(ctx + (size_t)b * 512 + h * 64 + g * 8) = ov;
  }
}

// ---------------- LayerNorm(tmp + h) -> h; GATHER also writes selected rows to hgat ----------------
template <int GATHER>
__global__ __launch_bounds__(256) void ln_kernel(const u16* __restrict__ t,
                                                 u16* __restrict__ h,
                                                 const float* __restrict__ gam,
                                                 const float* __restrict__ bet,
                                                 u16* __restrict__ hgat) {
  const int tid = threadIdx.x;
  const int wid = tid >> 6, lane = tid & 63;
  const int row = blockIdx.x * 4 + wid;
  const size_t base = (size_t)row * 512 + lane * 8;
  u16x8 tv = *(const u16x8*)(t + base);
  u16x8 hv = *(const u16x8*)(h + base);
  float x[8];
  float s1 = 0.f, s2 = 0.f;
#pragma unroll
  for (int e = 0; e < 8; ++e) {
    x[e] = b2f(tv[e]) + b2f(hv[e]);
    s1 += x[e];
    s2 += x[e] * x[e];
  }
#pragma unroll
  for (int m = 1; m < 64; m <<= 1) {
    s1 += __shfl_xor(s1, m);
    s2 += __shfl_xor(s2, m);
  }
  const float mu = s1 * (1.f / 512.f);
  const float var = s2 * (1.f / 512.f) - mu * mu;
  const float rs = rsqrtf(var + 1e-6f);
  const float4 g0 = *(const float4*)(gam + lane * 8);
  const float4 g1 = *(const float4*)(gam + lane * 8 + 4);
  const float4 b0 = *(const float4*)(bet + lane * 8);
  const float4 b1 = *(const float4*)(bet + lane * 8 + 4);
  const float gv[8] = {g0.x, g0.y, g0.z, g0.w, g1.x, g1.y, g1.z, g1.w};
  const float bv[8] = {b0.x, b0.y, b0.z, b0.w, b1.x, b1.y, b1.z, b1.w};
  u16x8 yv;
#pragma unroll
  for (int e = 0; e < 8; ++e) yv[e] = f2b((x[e] - mu) * rs * gv[e] + bv[e]);
  *(u16x8*)(h + base) = yv;
  if (GATHER) {
    const int bb = row >> 3;
    if ((row & 7) == (bb & 7))
      *(u16x8*)(hgat + (size_t)bb * 512 + lane * 8) = yv;
  }
}

// ---- layer-1 LN1: hsel[b] = LN(tmp_sel[b] + h[8b + (b&7)]) ----
__global__ __launch_bounds__(256) void ln_gather_kernel(const u16* __restrict__ t,
                                                        const u16* __restrict__ h,
                                                        u16* __restrict__ hsel,
                                                        const float* __restrict__ gam,
                                                        const float* __restrict__ bet) {
  const int tid = threadIdx.x;
  const int wid = tid >> 6, lane = tid & 63;
  const int b = blockIdx.x * 4 + wid;
  const size_t tb = (size_t)(b * 8 + (b & 7));
  u16x8 tv = *(const u16x8*)(t + (size_t)b * 512 + lane * 8);
  u16x8 hv = *(const u16x8*)(h + tb * 512 + lane * 8);
  float x[8];
  float s1 = 0.f, s2 = 0.f;
#pragma unroll
  for (int e = 0; e < 8; ++e) {
    x[e] = b2f(tv[e]) + b2f(hv[e]);
    s1 += x[e];
    s2 += x[e] * x[e];
  }
#pragma unroll
  for (int m = 1; m < 64; m <<= 1) {
    s1 += __shfl_xor(s1, m);
    s2 += __shfl_xor(s2, m);
  }
  const float mu = s1 * (1.f / 512.f);
  const float var = s2 * (1.f / 512.f) - mu * mu;
  const float rs = rsqrtf(var + 1e-6f);
  const float4 g0 = *(const float4*)(gam + lane * 8);
  const float4 g1 = *(const float4*)(gam + lane * 8 + 4);
  const float4 b0 = *(const float4*)(bet + lane * 8);
  const float4 b1 = *(const float4*)(bet + lane * 8 + 4);
  const float gv[8] = {g0.x, g0.y, g0.z, g0.w, g1.x, g1.y, g1.z, g1.w};
  const float bv[8] = {b0.x, b0.y, b0.z, b0.w, b1.x, b1.y, b1.z, b1.w};
  u16x8 yv;
#pragma unroll
  for (int e = 0; e < 8; ++e) yv[e] = f2b((x[e] - mu) * rs * gv[e] + bv[e]);
  *(u16x8*)(hsel + (size_t)b * 512 + lane * 8) = yv;
}

// ---- layer-1 LN2 + output: out[b] = LN(tmp_sel[b] + hsel[b]) (fp32) ----
__global__ __launch_bounds__(256) void ln_final_kernel(const u16* __restrict__ t,
                                                       const u16* __restrict__ hsel,
                                                       const float* __restrict__ gam,
                                                       const float* __restrict__ bet,
                                                       float* __restrict__ out) {
  const int tid = threadIdx.x;
  const int wid = tid >> 6, lane = tid & 63;
  const int b = blockIdx.x * 4 + wid;
  const size_t base = (size_t)b * 512 + lane * 8;
  u16x8 tv = *(const u16x8*)(t + base);
  u16x8 hv = *(const u16x8*)(hsel + base);
  float x[8];
  float s1 = 0.f, s2 = 0.f;
#pragma unroll
  for (int e = 0; e < 8; ++e) {
    x[e] = b2f(tv[e]) + b2f(hv[e]);
    s1 += x[e];
    s2 += x[e] * x[e];
  }
#pragma unroll
  for (int m = 1; m < 64; m <<= 1) {
    s1 += __shfl_xor(s1, m);
    s2 += __shfl_xor(s2, m);
  }
  const float mu = s1 * (1.f / 512.f);
  const float var = s2 * (1.f / 512.f) - mu * mu;
  const float rs = rsqrtf(var + 1e-6f);
  const float4 g0 = *(const float4*)(gam + lane * 8);
  const float4 g1 = *(const float4*)(gam + lane * 8 + 4);
  const float4 b0 = *(const float4*)(bet + lane * 8);
  const float4 b1 = *(const float4*)(bet + lane * 8 + 4);
  const float gv[8] = {g0.x, g0.y, g0.z, g0.w, g1.x, g1.y, g1.z, g1.w};
  const float bv[8] = {b0.x, b0.y, b0.z, b0.w, b1.x, b1.y, b1.z, b1.w};
  float y[8];
#pragma unroll
  for (int e = 0; e < 8; ++e) y[e] = (x[e] - mu) * rs * gv[e] + bv[e];
  float4* op = (float4*)(out + base);
  op[0] = make_float4(y[0], y[1], y[2], y[3]);
  op[1] = make_float4(y[4], y[5], y[6], y[7]);
}

static void launch_gemm(const u16* A, const u16* Bt, const float* bias, u16* C, int M, int N,
                        int K, int relu, hipStream_t st) {
  dim3 grid((M >> 8) * (N >> 8));
  if (relu)
    gemm256<1><<<grid, 512, 0, st>>>(A, Bt, bias, C, M, N, K);
  else
    gemm256<0><<<grid, 512, 0, st>>>(A, Bt, bias, C, M, N, K);
}

extern "C" void kernel_launch(void* const* d_in, const int* in_sizes, int n_in, void* d_out,
                              int out_size, void* d_ws, size_t ws_size, hipStream_t stream) {
  const float* x = (const float*)d_in[0];
  const float* Wq = (const float*)d_in[1];
  const float* bq = (const float*)d_in[2];
  const float* Wk = (const float*)d_in[3];
  const float* bk = (const float*)d_in[4];
  const float* Wv = (const float*)d_in[5];
  const float* bv = (const float*)d_in[6];
  const float* Wo = (const float*)d_in[7];
  const float* bo = (const float*)d_in[8];
  const float* ln1g = (const float*)d_in[9];
  const float* ln1b = (const float*)d_in[10];
  const float* W1 = (const float*)d_in[11];
  const float* b1 = (const float*)d_in[12];
  const float* W2 = (const float*)d_in[13];
  const float* b2 = (const float*)d_in[14];
  const float* ln2g = (const float*)d_in[15];
  const float* ln2b = (const float*)d_in[16];
  float* out = (float*)d_out;

  char* ws = (char*)d_ws;
  const size_t o_tab = 0;
  const size_t o_bqkv = 16384;
  const size_t o_w = 28672;
  const size_t o_h = o_w + 12582912;
  const size_t o_buf = o_h + (size_t)NTOK * 512 * 2;
  const size_t o_tmp = o_buf + (size_t)NTOK * 2048 * 2;
  const size_t o_hsel = o_tmp + (size_t)NTOK * 512 * 2;
  const size_t o_hgat = o_hsel + (size_t)NSEL * 512 * 2;
  const size_t need = o_hgat + (size_t)NSEL * 512 * 2;
  if (ws_size < need) return;

  float* tab = (float*)(ws + o_tab);
  float* bqkv = (float*)(ws + o_bqkv);
  u16* wbf = (u16*)(ws + o_w);
  u16* h = (u16*)(ws + o_h);
  u16* buf = (u16*)(ws + o_buf);
  u16* ctx = buf + (size_t)NTOK * 1536;
  u16* tmp = (u16*)(ws + o_tmp);
  u16* hsel = (u16*)(ws + o_hsel);
  u16* hgat = (u16*)(ws + o_hgat);

  table_kernel<<<16, 256, 0, stream>>>(tab);
  biaspack_kernel<<<12, 256, 0, stream>>>(bq, bk, bv, bqkv);

  TJobs jobs;
  int blk = 0, nj = 0;
  auto add = [&](const float* s, u16* dmat, int Ki, int Ni) {
    jobs.j[nj].src = s;
    jobs.j[nj].dst = dmat;
    jobs.j[nj].Ki = Ki;
    jobs.j[nj].Ni = Ni;
    jobs.j[nj].blk0 = blk;
    ++nj;
    blk += (Ki / 64) * (Ni / 64);
  };
  for (int l = 0; l < 2; ++l) {
    u16* wl = wbf + (size_t)l * 3145728;
    add(Wq + (size_t)l * 262144, wl, 512, 512);
    add(Wk + (size_t)l * 262144, wl + 262144, 512, 512);
    add(Wv + (size_t)l * 262144, wl + 524288, 512, 512);
    add(Wo + (size_t)l * 262144, wl + 786432, 512, 512);
    add(W1 + (size_t)l * 1048576, wl + 1048576, 512, 2048);
    add(W2 + (size_t)l * 1048576, wl + 2097152, 2048, 512);
  }
  wconv_kernel<<<blk, 256, 0, stream>>>(jobs);
  posenc_kernel<<<32768, 256, 0, stream>>>(x, tab, h);

  // ---------------- layer 0: full computation ----------------
  {
    u16* wl = wbf;
    launch_gemm(h, wl, bqkv, buf, NTOK, 1536, 512, 0, stream);
    attn_kernel<<<32768, 256, 0, stream>>>(buf, ctx);
    launch_gemm(ctx, wl + 786432, bo, tmp, NTOK, 512, 512, 0, stream);
    ln_kernel<0><<<32768, 256, 0, stream>>>(tmp, h, ln1g, ln1b, nullptr);
    launch_gemm(h, wl + 1048576, b1, buf, NTOK, 2048, 512, 1, stream);
    launch_gemm(buf, wl + 2097152, b2, tmp, NTOK, 512, 2048, 0, stream);
    // LN2 also emits the gathered selected rows for layer-1's Q projection
    ln_kernel<1><<<32768, 256, 0, stream>>>(tmp, h, ln2g, ln2b, hgat);
  }

  // ---------------- layer 1: Q only for selected tokens; KV for all ----------------
  {
    u16* wl = wbf + 3145728;
    u16* kv = buf;                             // [NTOK][1024]
    u16* qsel = buf + (size_t)NTOK * 1024;     // [NSEL][512]
    u16* ctx_sel = qsel + (size_t)NSEL * 512;  // [NSEL][512]
    u16* hid_sel = ctx_sel + (size_t)NSEL * 512;  // [NSEL][2048]
    u16* tmp_sel = tmp;
    // KV projection over all tokens (Wk^T || Wv^T contiguous at wl+262144; bk|bv at bqkv+2048)
    launch_gemm(h, wl + 262144, bqkv + 1536 + 512, kv, NTOK, 1024, 512, 0, stream);
    // Q projection over selected tokens only
    launch_gemm(hgat, wl, bqkv + 1536, qsel, NSEL, 512, 512, 0, stream);
    // attention for the selected row per (b, head)
    attn_sel_kernel<<<32768, 256, 0, stream>>>(kv, qsel, ctx_sel);
    // O-projection on selected tokens
    launch_gemm(ctx_sel, wl + 786432, bo + 512, tmp_sel, NSEL, 512, 512, 0, stream);
    // LN1 with gathered residual
    ln_gather_kernel<<<NSEL / 4, 256, 0, stream>>>(tmp_sel, h, hsel, ln1g + 512, ln1b + 512);
    // FFN1 (+ReLU) on selected
    launch_gemm(hsel, wl + 1048576, b1 + 2048, hid_sel, NSEL, 2048, 512, 1, stream);
    // FFN2 on selected
    launch_gemm(hid_sel, wl + 2097152, b2 + 512, tmp_sel, NSEL, 512, 2048, 0, stream);
    // LN2 + fp32 output
    ln_final_kernel<<<NSEL / 4, 256, 0, stream>>>(tmp_sel, hsel, ln2g + 512, ln2b + 512, out);
  }
}